// Round 8
// baseline (471.146 us; speedup 1.0000x reference)
//
#include <hip/hip_runtime.h>
#include <hip/hip_bf16.h>
#include <math.h>

#define NN 100000
#define NE 3200000
#define NPAD 100096
#define NB 391        // buckets: dst>>8, 256 nodes each
#define BN 256        // nodes per bucket
#define EPB 4096      // edges per block in hist/scatter passes
#define SBLK 782      // ceil(NE/EPB)

typedef __attribute__((ext_vector_type(8))) short short8;
typedef __attribute__((ext_vector_type(4))) float floatx4;
typedef _Float16 h2_t __attribute__((ext_vector_type(2)));

// ---------------- bf16 helpers (storage bf16, math fp32) ----------------
__device__ __forceinline__ unsigned short bf16_of(float x) {
    __hip_bfloat16 h = __float2bfloat16(x);  // RNE
    return *(unsigned short*)&h;
}
__device__ __forceinline__ unsigned pack2(float a, float b) {
    return (unsigned)bf16_of(a) | ((unsigned)bf16_of(b) << 16);
}
__device__ __forceinline__ float lo_f(unsigned u) { return __uint_as_float(u << 16); }
__device__ __forceinline__ float hi_f(unsigned u) { return __uint_as_float(u & 0xffff0000u); }
__device__ __forceinline__ void acc8(float* a, uint4 r) {
    a[0] += lo_f(r.x); a[1] += hi_f(r.x);
    a[2] += lo_f(r.y); a[3] += hi_f(r.y);
    a[4] += lo_f(r.z); a[5] += hi_f(r.z);
    a[6] += lo_f(r.w); a[7] += hi_f(r.w);
}

// ---------------- f16 helpers ----------------
__device__ __forceinline__ unsigned packh2(float a, float b) {
    unsigned short ua = __builtin_bit_cast(unsigned short, (_Float16)a);
    unsigned short ub = __builtin_bit_cast(unsigned short, (_Float16)b);
    return (unsigned)ua | ((unsigned)ub << 16);
}
__device__ __forceinline__ float dot2acc(unsigned a, unsigned b, float acc) {
#if __has_builtin(__builtin_amdgcn_fdot2)
    return __builtin_amdgcn_fdot2(__builtin_bit_cast(h2_t, a),
                                  __builtin_bit_cast(h2_t, b), acc, false);
#else
    h2_t ha = __builtin_bit_cast(h2_t, a), hb = __builtin_bit_cast(h2_t, b);
    return acc + (float)ha[0] * (float)hb[0] + (float)ha[1] * (float)hb[1];
#endif
}

// ---------------- pass A: per-block bucket histogram (bucket-major out) ----------------
__global__ __launch_bounds__(256) void hist_kernel(const int* __restrict__ dst,
                                                   int* __restrict__ blkhist) {
    __shared__ int cnt[NB];
    int t = threadIdx.x;
    for (int i = t; i < NB; i += 256) cnt[i] = 0;
    __syncthreads();
    int e0 = blockIdx.x * EPB;
    int e1 = min(e0 + EPB, NE);
    for (int e = e0 + t; e < e1; e += 256) atomicAdd(&cnt[dst[e] >> 8], 1);
    __syncthreads();
    for (int i = t; i < NB; i += 256) blkhist[i * SBLK + blockIdx.x] = cnt[i];
}

// ---------------- pass B1: per-bucket exclusive scan along blocks ----------------
__global__ __launch_bounds__(64) void scanA_kernel(int* __restrict__ blkhist,
                                                   int* __restrict__ totals) {
    int j = blockIdx.x, lane = threadIdx.x;
    int base = j * SBLK;
    int carry = 0;
    for (int c = 0; c < SBLK; c += 64) {
        int b = c + lane;
        int v = (b < SBLK) ? blkhist[base + b] : 0;
        int inc = v;
#pragma unroll
        for (int m = 1; m < 64; m <<= 1) {
            int u = __shfl_up(inc, m, 64);
            if (lane >= m) inc += u;
        }
        if (b < SBLK) blkhist[base + b] = carry + inc - v;
        carry += __shfl(inc, 63, 64);
    }
    if (lane == 0) totals[j] = carry;
}

// ---------------- pass B2: bucket bases ----------------
__global__ __launch_bounds__(256) void scanB_kernel(const int* __restrict__ totals,
                                                    int* __restrict__ bucket_base) {
    __shared__ int sm[NB];
    int t = threadIdx.x;
    for (int i = t; i < NB; i += 256) sm[i] = totals[i];
    __syncthreads();
    if (t == 0) {
        int r = 0;
        for (int i = 0; i < NB; ++i) { bucket_base[i] = r; r += sm[i]; }
        bucket_base[NB] = r;
    }
}

// ---------------- pass C: LDS-staged scatter -> contiguous run writes of {pack,eid} ----
__global__ __launch_bounds__(256) void scatter_kernel(const int* __restrict__ src,
                                                      const int* __restrict__ dst,
                                                      const int* __restrict__ blkhist,
                                                      const int* __restrict__ bucket_base,
                                                      int2* __restrict__ staged) {
    __shared__ int cnt[NB];
    __shared__ int lbase[NB + 1];
    __shared__ int gbase[NB];
    __shared__ int2 sbuf[EPB];            // 32KB
    __shared__ unsigned short sbkt[EPB];  // 8KB
    int t = threadIdx.x;
    for (int i = t; i < NB; i += 256) cnt[i] = 0;
    __syncthreads();
    int e0 = blockIdx.x * EPB;
    int e1 = min(e0 + EPB, NE);
    int cn = e1 - e0;
    for (int e = e0 + t; e < e1; e += 256) atomicAdd(&cnt[dst[e] >> 8], 1);
    __syncthreads();
    if (t < 64) {  // exclusive scan of 391 counts, 7 per lane
        int v[7]; int s = 0;
#pragma unroll
        for (int k = 0; k < 7; ++k) { int idx = t * 7 + k; v[k] = (idx < NB) ? cnt[idx] : 0; s += v[k]; }
        int inc = s;
#pragma unroll
        for (int m = 1; m < 64; m <<= 1) {
            int u = __shfl_up(inc, m, 64);
            if (t >= m) inc += u;
        }
        int run = inc - s;
#pragma unroll
        for (int k = 0; k < 7; ++k) { int idx = t * 7 + k; if (idx < NB) lbase[idx] = run; run += v[k]; }
        if (t == 63) lbase[NB] = inc;  // == cn
    }
    __syncthreads();
    for (int i = t; i < NB; i += 256) {
        gbase[i] = bucket_base[i] + blkhist[i * SBLK + blockIdx.x];
        cnt[i] = lbase[i];            // rank cursors
    }
    __syncthreads();
    for (int e = e0 + t; e < e1; e += 256) {
        int s = src[e], d = dst[e];
        int bk = d >> 8;
        int r = atomicAdd(&cnt[bk], 1);     // LDS atomic
        sbuf[r] = make_int2((s << 8) | (d & (BN - 1)), e);
        sbkt[r] = (unsigned short)bk;
    }
    __syncthreads();
    for (int i = t; i < cn; i += 256) {     // contiguous run write-out
        int bk = sbkt[i];
        staged[gbase[bk] + i - lbase[bk]] = sbuf[i];
    }
}

// ---------------- pass D: per-bucket fine counting sort + offsets + dis + eid -----
__global__ __launch_bounds__(256) void fine_kernel(const int2* __restrict__ staged,
                                                   const int* __restrict__ bucket_base,
                                                   int* __restrict__ offset,
                                                   float* __restrict__ dis,
                                                   int* __restrict__ csr_src,
                                                   int* __restrict__ csr_eid) {
    __shared__ int hist[BN];
    __shared__ int offs[BN];
    __shared__ int cur[BN];
    int t = threadIdx.x, j = blockIdx.x;
    int bb = bucket_base[j], be = bucket_base[j + 1];
    int cn = be - bb;
    for (int i = t; i < BN; i += 256) hist[i] = 0;
    __syncthreads();
    for (int e = t; e < cn; e += 256) atomicAdd(&hist[staged[bb + e].x & (BN - 1)], 1);
    __syncthreads();
    if (t < 64) {  // wave0: exclusive scan of 256 counts
        int v[4]; int s = 0;
#pragma unroll
        for (int k = 0; k < 4; ++k) { v[k] = hist[t * 4 + k]; s += v[k]; }
        int inc = s;
#pragma unroll
        for (int m = 1; m < 64; m <<= 1) {
            int u = __shfl_up(inc, m, 64);
            if (t >= m) inc += u;
        }
        int run = inc - s;
#pragma unroll
        for (int k = 0; k < 4; ++k) { offs[t * 4 + k] = run; run += v[k]; }
    }
    __syncthreads();
    if (t < BN) {
        cur[t] = offs[t];
        int n = j * BN + t;
        if (n < NN) {
            offset[n] = bb + offs[t];
            dis[n] = rsqrtf((float)hist[t] + 1.0f);
        }
    }
    if (j == NB - 1 && t == 0) offset[NN] = NE;
    __syncthreads();
    for (int e = t; e < cn; e += 256) {
        int2 p = staged[bb + e];
        int r = atomicAdd(&cur[p.x & (BN - 1)], 1);  // LDS atomic
        csr_src[bb + r] = p.x >> 8;
        csr_eid[bb + r] = p.y;
    }
}

// ---------------- matmul 1 (MFMA): ys1 = bf16(dis * (x @ W1)) ----------------
__global__ __launch_bounds__(256) void mm1_kernel(const float* __restrict__ x,
                                                  const float* __restrict__ W,
                                                  const float* __restrict__ dis,
                                                  unsigned short* __restrict__ y) {
    __shared__ unsigned short Wt[64][136];  // W^T bf16: [n][k], pad 8 shorts
    int t = threadIdx.x;
    for (int i = t; i < 128 * 64; i += 256) {
        int k = i >> 6, n = i & 63;
        Wt[n][k] = bf16_of(W[i]);
    }
    __syncthreads();
    int wave = t >> 6, lane = t & 63;
    int quad = lane >> 4, n16 = lane & 15;
    short8 bfr[4][4];  // [kstep][coltile]
#pragma unroll
    for (int s = 0; s < 4; ++s)
#pragma unroll
        for (int tt = 0; tt < 4; ++tt)
            bfr[s][tt] = *(const short8*)&Wt[tt * 16 + n16][s * 32 + quad * 8];
    int tile0 = (blockIdx.x * 4 + wave) * 4;   // 391 blocks x 4 waves x 4 tiles >= 6250
#pragma unroll 1
    for (int it = 0; it < 4; ++it) {
        int tile = tile0 + it;
        if (tile >= 6250) break;
        int m0 = tile * 16;
        const float* xp = x + (size_t)(m0 + n16) * 128 + quad * 8;
        floatx4 acc0 = {0,0,0,0}, acc1 = {0,0,0,0}, acc2 = {0,0,0,0}, acc3 = {0,0,0,0};
#pragma unroll
        for (int s = 0; s < 4; ++s) {
            float4 lo = *(const float4*)(xp + s * 32);
            float4 hi = *(const float4*)(xp + s * 32 + 4);
            short8 a;
            a[0] = (short)bf16_of(lo.x); a[1] = (short)bf16_of(lo.y);
            a[2] = (short)bf16_of(lo.z); a[3] = (short)bf16_of(lo.w);
            a[4] = (short)bf16_of(hi.x); a[5] = (short)bf16_of(hi.y);
            a[6] = (short)bf16_of(hi.z); a[7] = (short)bf16_of(hi.w);
            acc0 = __builtin_amdgcn_mfma_f32_16x16x32_bf16(a, bfr[s][0], acc0, 0, 0, 0);
            acc1 = __builtin_amdgcn_mfma_f32_16x16x32_bf16(a, bfr[s][1], acc1, 0, 0, 0);
            acc2 = __builtin_amdgcn_mfma_f32_16x16x32_bf16(a, bfr[s][2], acc2, 0, 0, 0);
            acc3 = __builtin_amdgcn_mfma_f32_16x16x32_bf16(a, bfr[s][3], acc3, 0, 0, 0);
        }
#pragma unroll
        for (int r = 0; r < 4; ++r) {
            int ro = m0 + quad * 4 + r;
            float sc = dis[ro];
            unsigned short* yp = y + (size_t)ro * 64 + n16;
            yp[0]  = bf16_of(acc0[r] * sc);
            yp[16] = bf16_of(acc1[r] * sc);
            yp[32] = bf16_of(acc2[r] * sc);
            yp[48] = bf16_of(acc3[r] * sc);
        }
    }
}

// ---------------- matmul 2 (MFMA): ys2 = bf16(dis * (h @ W2)), h bf16 ----------------
__global__ __launch_bounds__(256) void mm2_kernel(const unsigned short* __restrict__ h,
                                                  const float* __restrict__ W,
                                                  const float* __restrict__ dis,
                                                  unsigned short* __restrict__ y) {
    __shared__ unsigned short Wt[32][72];  // W^T bf16: [n][k], pad 8
    int t = threadIdx.x;
    for (int i = t; i < 64 * 32; i += 256) {
        int k = i >> 5, n = i & 31;
        Wt[n][k] = bf16_of(W[i]);
    }
    __syncthreads();
    int wave = t >> 6, lane = t & 63;
    int quad = lane >> 4, n16 = lane & 15;
    short8 bfr[2][2];
#pragma unroll
    for (int s = 0; s < 2; ++s)
#pragma unroll
        for (int tt = 0; tt < 2; ++tt)
            bfr[s][tt] = *(const short8*)&Wt[tt * 16 + n16][s * 32 + quad * 8];
    int tile0 = (blockIdx.x * 4 + wave) * 4;
#pragma unroll 1
    for (int it = 0; it < 4; ++it) {
        int tile = tile0 + it;
        if (tile >= 6250) break;
        int m0 = tile * 16;
        const unsigned short* hp = h + (size_t)(m0 + n16) * 64 + quad * 8;
        floatx4 acc0 = {0,0,0,0}, acc1 = {0,0,0,0};
#pragma unroll
        for (int s = 0; s < 2; ++s) {
            short8 a = *(const short8*)(hp + s * 32);
            acc0 = __builtin_amdgcn_mfma_f32_16x16x32_bf16(a, bfr[s][0], acc0, 0, 0, 0);
            acc1 = __builtin_amdgcn_mfma_f32_16x16x32_bf16(a, bfr[s][1], acc1, 0, 0, 0);
        }
#pragma unroll
        for (int r = 0; r < 4; ++r) {
            int ro = m0 + quad * 4 + r;
            float sc = dis[ro];
            unsigned short* yp = y + (size_t)ro * 32 + n16;
            yp[0]  = bf16_of(acc0[r] * sc);
            yp[16] = bf16_of(acc1[r] * sc);
        }
    }
}

// ---------------- fused gather-aggregate, dim 64 bf16 -> h bf16, unroll 8 ----------------
__global__ __launch_bounds__(256) void agg64_kernel(const uint4* __restrict__ ys4,
                                                    const float* __restrict__ dis,
                                                    const int* __restrict__ offset,
                                                    const int* __restrict__ csr_src,
                                                    const float* __restrict__ b,
                                                    uint4* __restrict__ h4) {
    int tid = blockIdx.x * 256 + threadIdx.x;
    int nd = tid >> 3, c = tid & 7;
    if (nd >= NN) return;
    int start = offset[nd], end = offset[nd + 1];
    float acc[8] = {0, 0, 0, 0, 0, 0, 0, 0};
    acc8(acc, ys4[(size_t)nd * 8 + c]);  // self-loop term
    int i = start;
    int n8 = start + ((end - start) & ~7);
    for (; i < n8; i += 8) {
        int s0 = csr_src[i],     s1 = csr_src[i + 1], s2 = csr_src[i + 2], s3 = csr_src[i + 3];
        int s4 = csr_src[i + 4], s5 = csr_src[i + 5], s6 = csr_src[i + 6], s7 = csr_src[i + 7];
        uint4 r0 = ys4[(size_t)s0 * 8 + c];
        uint4 r1 = ys4[(size_t)s1 * 8 + c];
        uint4 r2 = ys4[(size_t)s2 * 8 + c];
        uint4 r3 = ys4[(size_t)s3 * 8 + c];
        uint4 r4 = ys4[(size_t)s4 * 8 + c];
        uint4 r5 = ys4[(size_t)s5 * 8 + c];
        uint4 r6 = ys4[(size_t)s6 * 8 + c];
        uint4 r7 = ys4[(size_t)s7 * 8 + c];
        acc8(acc, r0); acc8(acc, r1); acc8(acc, r2); acc8(acc, r3);
        acc8(acc, r4); acc8(acc, r5); acc8(acc, r6); acc8(acc, r7);
    }
    for (; i < end; ++i) acc8(acc, ys4[(size_t)csr_src[i] * 8 + c]);
    float ds = dis[nd];
    const float4 bv0 = *(const float4*)&b[c * 8];
    const float4 bv1 = *(const float4*)&b[c * 8 + 4];
    uint4 o;
    o.x = pack2(fmaxf(fmaf(ds, acc[0], bv0.x), 0.f), fmaxf(fmaf(ds, acc[1], bv0.y), 0.f));
    o.y = pack2(fmaxf(fmaf(ds, acc[2], bv0.z), 0.f), fmaxf(fmaf(ds, acc[3], bv0.w), 0.f));
    o.z = pack2(fmaxf(fmaf(ds, acc[4], bv1.x), 0.f), fmaxf(fmaf(ds, acc[5], bv1.y), 0.f));
    o.w = pack2(fmaxf(fmaf(ds, acc[6], bv1.z), 0.f), fmaxf(fmaf(ds, acc[7], bv1.w), 0.f));
    h4[(size_t)nd * 8 + c] = o;
}

// ---------------- fused gather-aggregate, dim 32 bf16 -> z f16, unroll 8 ----------------
__global__ __launch_bounds__(256) void agg32_kernel(const uint4* __restrict__ ys4,
                                                    const float* __restrict__ dis,
                                                    const int* __restrict__ offset,
                                                    const int* __restrict__ csr_src,
                                                    const float* __restrict__ b,
                                                    uint4* __restrict__ z4) {
    int tid = blockIdx.x * 256 + threadIdx.x;
    int nd = tid >> 2, c = tid & 3;
    if (nd >= NN) return;
    int start = offset[nd], end = offset[nd + 1];
    float acc[8] = {0, 0, 0, 0, 0, 0, 0, 0};
    acc8(acc, ys4[(size_t)nd * 4 + c]);
    int i = start;
    int n8 = start + ((end - start) & ~7);
    for (; i < n8; i += 8) {
        int s0 = csr_src[i],     s1 = csr_src[i + 1], s2 = csr_src[i + 2], s3 = csr_src[i + 3];
        int s4 = csr_src[i + 4], s5 = csr_src[i + 5], s6 = csr_src[i + 6], s7 = csr_src[i + 7];
        uint4 r0 = ys4[(size_t)s0 * 4 + c];
        uint4 r1 = ys4[(size_t)s1 * 4 + c];
        uint4 r2 = ys4[(size_t)s2 * 4 + c];
        uint4 r3 = ys4[(size_t)s3 * 4 + c];
        uint4 r4 = ys4[(size_t)s4 * 4 + c];
        uint4 r5 = ys4[(size_t)s5 * 4 + c];
        uint4 r6 = ys4[(size_t)s6 * 4 + c];
        uint4 r7 = ys4[(size_t)s7 * 4 + c];
        acc8(acc, r0); acc8(acc, r1); acc8(acc, r2); acc8(acc, r3);
        acc8(acc, r4); acc8(acc, r5); acc8(acc, r6); acc8(acc, r7);
    }
    for (; i < end; ++i) acc8(acc, ys4[(size_t)csr_src[i] * 4 + c]);
    float ds = dis[nd];
    const float4 bv0 = *(const float4*)&b[c * 8];
    const float4 bv1 = *(const float4*)&b[c * 8 + 4];
    uint4 o;  // z stored f16
    o.x = packh2(fmaf(ds, acc[0], bv0.x), fmaf(ds, acc[1], bv0.y));
    o.y = packh2(fmaf(ds, acc[2], bv0.z), fmaf(ds, acc[3], bv0.w));
    o.z = packh2(fmaf(ds, acc[4], bv1.x), fmaf(ds, acc[5], bv1.y));
    o.w = packh2(fmaf(ds, acc[6], bv1.z), fmaf(ds, acc[7], bv1.w));
    z4[(size_t)nd * 4 + c] = o;
}

// ---------------- decode (CSR order): one wave per dst node; z[dst] broadcast ------
// 16 groups x 4 lanes; group g handles CSR slots start+g, start+g+16, ...
__global__ __launch_bounds__(256) void decode_kernel(const uint4* __restrict__ z4,
                                                     const int* __restrict__ offset,
                                                     const int* __restrict__ csr_src,
                                                     const int* __restrict__ csr_eid,
                                                     float* __restrict__ out) {
    int wv = (blockIdx.x * 256 + threadIdx.x) >> 6;  // wave id == dst node
    if (wv >= NN) return;
    int lane = threadIdx.x & 63, g = lane >> 2, k = lane & 3;
    uint4 zd = z4[(size_t)wv * 4 + k];   // 4 distinct 16B addrs per wave (broadcast)
    int start = offset[wv], end = offset[wv + 1];
    for (int i = start + g; i < end; i += 16) {
        int s = csr_src[i];
        uint4 za = z4[(size_t)s * 4 + k];
        float acc = dot2acc(za.x, zd.x, 0.f);
        acc = dot2acc(za.y, zd.y, acc);
        acc = dot2acc(za.z, zd.z, acc);
        acc = dot2acc(za.w, zd.w, acc);
        acc += __shfl_xor(acc, 1, 4);
        acc += __shfl_xor(acc, 2, 4);
        if (k == 0) out[csr_eid[i]] = 1.0f / (1.0f + expf(-acc));
    }
}

// ---------------- launcher ----------------
extern "C" void kernel_launch(void* const* d_in, const int* in_sizes, int n_in,
                              void* d_out, int out_size, void* d_ws, size_t ws_size,
                              hipStream_t stream) {
    const float* emb = (const float*)d_in[0];
    const float* W1  = (const float*)d_in[1];
    const float* b1  = (const float*)d_in[2];
    const float* W2  = (const float*)d_in[3];
    const float* b2  = (const float*)d_in[4];
    const int*   ei  = (const int*)d_in[5];
    const int* src = ei;
    const int* dst = ei + NE;
    float* out = (float*)d_out;

    // workspace layout
    char* w = (char*)d_ws;
    int*   offset      = (int*)w;           w += (size_t)NPAD * 4;
    float* dis         = (float*)w;         w += (size_t)NPAD * 4;
    int*   bucket_base = (int*)w;           w += 2048;
    int*   totals      = (int*)w;           w += 2048;
    int*   blkhist     = (int*)w;           w += (size_t)NB * SBLK * 4 + 1024;  // ~1.2MB
    int*   csr_src     = (int*)w;           w += (size_t)NE * 4;                // 12.8MB
    int*   csr_eid     = (int*)w;           w += (size_t)NE * 4;                // 12.8MB
    int2*  staged      = (int2*)w;          w += (size_t)NE * 8;                // 25.6MB
    unsigned short* ysbuf = (unsigned short*)w; w += (size_t)NN * 64 * 2;       // 12.8MB
    unsigned short* h  = (unsigned short*)w;                                    // 12.8MB
    unsigned short* ys1 = ysbuf;                       // [NN][64] bf16
    unsigned short* ys2 = ysbuf;                       // [NN][32] bf16 (overlay)
    unsigned short* z   = ysbuf + (size_t)NN * 32;     // [NN][32] f16 (2nd half)

    // CSR build — LDS atomics only, contiguous staged writes, carries eid
    hist_kernel<<<SBLK, 256, 0, stream>>>(dst, blkhist);
    scanA_kernel<<<NB, 64, 0, stream>>>(blkhist, totals);
    scanB_kernel<<<1, 256, 0, stream>>>(totals, bucket_base);
    scatter_kernel<<<SBLK, 256, 0, stream>>>(src, dst, blkhist, bucket_base, staged);
    fine_kernel<<<NB, 256, 0, stream>>>(staged, bucket_base, offset, dis, csr_src, csr_eid);

    // layer 1
    mm1_kernel<<<391, 256, 0, stream>>>(emb, W1, dis, ys1);
    agg64_kernel<<<(NN * 8) / 256, 256, 0, stream>>>((const uint4*)ys1, dis, offset, csr_src, b1, (uint4*)h);

    // layer 2
    mm2_kernel<<<391, 256, 0, stream>>>(h, W2, dis, ys2);
    agg32_kernel<<<(NN * 4 + 255) / 256, 256, 0, stream>>>((const uint4*)ys2, dis, offset, csr_src, b2, (uint4*)z);

    // decode in CSR order (z[dst] in registers; out scattered via eid)
    decode_kernel<<<(NN * 64 + 255) / 256, 256, 0, stream>>>((const uint4*)z, offset, csr_src, csr_eid, out);
}

// Round 9
// 406.881 us; speedup vs baseline: 1.1579x; 1.1579x over previous
//
#include <hip/hip_runtime.h>
#include <hip/hip_bf16.h>
#include <math.h>

#define NN 100000
#define NE 3200000
#define NPAD 100096
#define BN 128        // nodes per bucket
#define NB 782        // ceil(NN/BN)
#define EPB 6144      // edges per block in hist/scatter passes
#define SBLK 521      // ceil(NE/EPB)
#define SBUF 5120     // LDS sorted-segment capacity (mean 4096, sigma~64 -> +16 sigma)

typedef __attribute__((ext_vector_type(8))) short short8;
typedef __attribute__((ext_vector_type(4))) float floatx4;
typedef _Float16 h2_t __attribute__((ext_vector_type(2)));

// ---------------- bf16 helpers (storage bf16, math fp32) ----------------
__device__ __forceinline__ unsigned short bf16_of(float x) {
    __hip_bfloat16 h = __float2bfloat16(x);  // RNE
    return *(unsigned short*)&h;
}
__device__ __forceinline__ unsigned pack2(float a, float b) {
    return (unsigned)bf16_of(a) | ((unsigned)bf16_of(b) << 16);
}
__device__ __forceinline__ float lo_f(unsigned u) { return __uint_as_float(u << 16); }
__device__ __forceinline__ float hi_f(unsigned u) { return __uint_as_float(u & 0xffff0000u); }
__device__ __forceinline__ void acc8(float* a, uint4 r) {
    a[0] += lo_f(r.x); a[1] += hi_f(r.x);
    a[2] += lo_f(r.y); a[3] += hi_f(r.y);
    a[4] += lo_f(r.z); a[5] += hi_f(r.z);
    a[6] += lo_f(r.w); a[7] += hi_f(r.w);
}

// ---------------- f16 helpers ----------------
__device__ __forceinline__ unsigned packh2(float a, float b) {
    unsigned short ua = __builtin_bit_cast(unsigned short, (_Float16)a);
    unsigned short ub = __builtin_bit_cast(unsigned short, (_Float16)b);
    return (unsigned)ua | ((unsigned)ub << 16);
}
__device__ __forceinline__ float dot2acc(unsigned a, unsigned b, float acc) {
#if __has_builtin(__builtin_amdgcn_fdot2)
    return __builtin_amdgcn_fdot2(__builtin_bit_cast(h2_t, a),
                                  __builtin_bit_cast(h2_t, b), acc, false);
#else
    h2_t ha = __builtin_bit_cast(h2_t, a), hb = __builtin_bit_cast(h2_t, b);
    return acc + (float)ha[0] * (float)hb[0] + (float)ha[1] * (float)hb[1];
#endif
}

// ---------------- pass A: per-block bucket histogram (bucket-major out) ----------------
__global__ __launch_bounds__(256) void hist_kernel(const int* __restrict__ dst,
                                                   int* __restrict__ blkhist) {
    __shared__ int cnt[NB];
    int t = threadIdx.x;
    for (int i = t; i < NB; i += 256) cnt[i] = 0;
    __syncthreads();
    int e0 = blockIdx.x * EPB;
    int e1 = min(e0 + EPB, NE);
    for (int e = e0 + t; e < e1; e += 256) atomicAdd(&cnt[dst[e] >> 7], 1);
    __syncthreads();
    for (int i = t; i < NB; i += 256) blkhist[i * SBLK + blockIdx.x] = cnt[i];
}

// ---------------- pass B1: per-bucket exclusive scan along blocks ----------------
__global__ __launch_bounds__(64) void scanA_kernel(int* __restrict__ blkhist,
                                                   int* __restrict__ totals) {
    int j = blockIdx.x, lane = threadIdx.x;
    int base = j * SBLK;
    int carry = 0;
    for (int c = 0; c < SBLK; c += 64) {
        int b = c + lane;
        int v = (b < SBLK) ? blkhist[base + b] : 0;
        int inc = v;
#pragma unroll
        for (int m = 1; m < 64; m <<= 1) {
            int u = __shfl_up(inc, m, 64);
            if (lane >= m) inc += u;
        }
        if (b < SBLK) blkhist[base + b] = carry + inc - v;
        carry += __shfl(inc, 63, 64);
    }
    if (lane == 0) totals[j] = carry;
}

// ---------------- pass B2: bucket bases (64-lane chunked scan over NB) ----------------
__global__ __launch_bounds__(64) void scanB_kernel(const int* __restrict__ totals,
                                                   int* __restrict__ bucket_base) {
    int lane = threadIdx.x;
    int carry = 0;
    for (int c = 0; c < NB; c += 64) {
        int idx = c + lane;
        int v = (idx < NB) ? totals[idx] : 0;
        int inc = v;
#pragma unroll
        for (int m = 1; m < 64; m <<= 1) {
            int u = __shfl_up(inc, m, 64);
            if (lane >= m) inc += u;
        }
        if (idx < NB) bucket_base[idx] = carry + inc - v;
        carry += __shfl(inc, 63, 64);
    }
    if (lane == 0) bucket_base[NB] = carry;  // == NE
}

// ---------------- pass C: LDS-staged scatter -> contiguous run writes ----------------
__global__ __launch_bounds__(256) void scatter_kernel(const int* __restrict__ src,
                                                      const int* __restrict__ dst,
                                                      const int* __restrict__ blkhist,
                                                      const int* __restrict__ bucket_base,
                                                      int* __restrict__ staged) {
    __shared__ int cnt[NB];
    __shared__ int lbase[NB + 1];
    __shared__ int gbase[NB];
    __shared__ int sbuf[EPB];             // 24KB
    __shared__ unsigned short sbkt[EPB];  // 12KB
    int t = threadIdx.x;
    for (int i = t; i < NB; i += 256) cnt[i] = 0;
    __syncthreads();
    int e0 = blockIdx.x * EPB;
    int e1 = min(e0 + EPB, NE);
    int cn = e1 - e0;
    for (int e = e0 + t; e < e1; e += 256) atomicAdd(&cnt[dst[e] >> 7], 1);
    __syncthreads();
    if (t < 64) {  // chunked exclusive scan of NB counts
        int carry = 0;
        for (int c = 0; c < NB; c += 64) {
            int idx = c + t;
            int v = (idx < NB) ? cnt[idx] : 0;
            int inc = v;
#pragma unroll
            for (int m = 1; m < 64; m <<= 1) {
                int u = __shfl_up(inc, m, 64);
                if (t >= m) inc += u;
            }
            if (idx < NB) lbase[idx] = carry + inc - v;
            carry += __shfl(inc, 63, 64);
        }
        if (t == 0) lbase[NB] = carry;  // == cn
    }
    __syncthreads();
    for (int i = t; i < NB; i += 256) {
        gbase[i] = bucket_base[i] + blkhist[i * SBLK + blockIdx.x];
        cnt[i] = lbase[i];            // rank cursors
    }
    __syncthreads();
    for (int e = e0 + t; e < e1; e += 256) {
        int s = src[e], d = dst[e];
        int bk = d >> 7;
        int r = atomicAdd(&cnt[bk], 1);     // LDS atomic
        sbuf[r] = (s << 7) | (d & (BN - 1));
        sbkt[r] = (unsigned short)bk;
    }
    __syncthreads();
    for (int i = t; i < cn; i += 256) {     // contiguous run write-out
        int bk = sbkt[i];
        staged[gbase[bk] + i - lbase[bk]] = sbuf[i];
    }
}

// ---------------- pass D: per-bucket degree/offset/dis (one staged read) ----------------
__global__ __launch_bounds__(256) void degdis_kernel(const int* __restrict__ staged,
                                                     const int* __restrict__ bucket_base,
                                                     int* __restrict__ offset,
                                                     float* __restrict__ dis) {
    __shared__ int hist[BN];
    __shared__ int offs[BN];
    int t = threadIdx.x, j = blockIdx.x;
    int bb = bucket_base[j], be = bucket_base[j + 1];
    if (t < BN) hist[t] = 0;
    __syncthreads();
    for (int e = bb + t; e < be; e += 256) atomicAdd(&hist[staged[e] & (BN - 1)], 1);
    __syncthreads();
    if (t < 64) {  // exclusive scan of 128 counts, 2 per lane
        int v0 = hist[t * 2], v1 = hist[t * 2 + 1];
        int s = v0 + v1;
        int inc = s;
#pragma unroll
        for (int m = 1; m < 64; m <<= 1) {
            int u = __shfl_up(inc, m, 64);
            if (t >= m) inc += u;
        }
        int run = inc - s;
        offs[t * 2] = run;
        offs[t * 2 + 1] = run + v0;
    }
    __syncthreads();
    if (t < BN) {
        int n = j * BN + t;
        if (n < NN) {
            offset[n] = bb + offs[t];
            dis[n] = rsqrtf((float)hist[t] + 1.0f);
        }
    }
    if (j == NB - 1 && t == 0) offset[NN] = NE;
}

// ---------------- matmul 1 (MFMA): ys1 = bf16(dis * (x @ W1)) ----------------
__global__ __launch_bounds__(256) void mm1_kernel(const float* __restrict__ x,
                                                  const float* __restrict__ W,
                                                  const float* __restrict__ dis,
                                                  unsigned short* __restrict__ y) {
    __shared__ unsigned short Wt[64][136];  // W^T bf16: [n][k], pad 8 shorts
    int t = threadIdx.x;
    for (int i = t; i < 128 * 64; i += 256) {
        int k = i >> 6, n = i & 63;
        Wt[n][k] = bf16_of(W[i]);
    }
    __syncthreads();
    int wave = t >> 6, lane = t & 63;
    int quad = lane >> 4, n16 = lane & 15;
    short8 bfr[4][4];  // [kstep][coltile]
#pragma unroll
    for (int s = 0; s < 4; ++s)
#pragma unroll
        for (int tt = 0; tt < 4; ++tt)
            bfr[s][tt] = *(const short8*)&Wt[tt * 16 + n16][s * 32 + quad * 8];
    int tile0 = (blockIdx.x * 4 + wave) * 4;   // 391 blocks x 4 waves x 4 tiles >= 6250
#pragma unroll 1
    for (int it = 0; it < 4; ++it) {
        int tile = tile0 + it;
        if (tile >= 6250) break;
        int m0 = tile * 16;
        const float* xp = x + (size_t)(m0 + n16) * 128 + quad * 8;
        floatx4 acc0 = {0,0,0,0}, acc1 = {0,0,0,0}, acc2 = {0,0,0,0}, acc3 = {0,0,0,0};
#pragma unroll
        for (int s = 0; s < 4; ++s) {
            float4 lo = *(const float4*)(xp + s * 32);
            float4 hi = *(const float4*)(xp + s * 32 + 4);
            short8 a;
            a[0] = (short)bf16_of(lo.x); a[1] = (short)bf16_of(lo.y);
            a[2] = (short)bf16_of(lo.z); a[3] = (short)bf16_of(lo.w);
            a[4] = (short)bf16_of(hi.x); a[5] = (short)bf16_of(hi.y);
            a[6] = (short)bf16_of(hi.z); a[7] = (short)bf16_of(hi.w);
            acc0 = __builtin_amdgcn_mfma_f32_16x16x32_bf16(a, bfr[s][0], acc0, 0, 0, 0);
            acc1 = __builtin_amdgcn_mfma_f32_16x16x32_bf16(a, bfr[s][1], acc1, 0, 0, 0);
            acc2 = __builtin_amdgcn_mfma_f32_16x16x32_bf16(a, bfr[s][2], acc2, 0, 0, 0);
            acc3 = __builtin_amdgcn_mfma_f32_16x16x32_bf16(a, bfr[s][3], acc3, 0, 0, 0);
        }
#pragma unroll
        for (int r = 0; r < 4; ++r) {
            int ro = m0 + quad * 4 + r;
            float sc = dis[ro];
            unsigned short* yp = y + (size_t)ro * 64 + n16;
            yp[0]  = bf16_of(acc0[r] * sc);
            yp[16] = bf16_of(acc1[r] * sc);
            yp[32] = bf16_of(acc2[r] * sc);
            yp[48] = bf16_of(acc3[r] * sc);
        }
    }
}

// ---------------- fused sort+aggregate, dim 64: per 128-node bucket ----------------
// Phase B sorts the bucket's staged segment into LDS (cursors from offset[]);
// phase C persists csr_src (coalesced, for agg32); phase D aggregates from LDS.
__global__ __launch_bounds__(256) void aggsort64_kernel(const int* __restrict__ staged,
                                                        const int* __restrict__ bucket_base,
                                                        const int* __restrict__ offset,
                                                        const uint4* __restrict__ ys4,
                                                        const float* __restrict__ b,
                                                        int* __restrict__ csr_src,
                                                        uint4* __restrict__ h4) {
    __shared__ int offs[BN + 1];
    __shared__ int cur[BN];
    __shared__ int sb[SBUF];   // 20KB
    int t = threadIdx.x, j = blockIdx.x;
    int bb = bucket_base[j], be = bucket_base[j + 1];
    int cn = be - bb;
    bool lds_ok = (cn <= SBUF);
    if (t < BN + 1) {
        int idx = j * BN + t;
        if (idx > NN) idx = NN;
        offs[t] = offset[idx];
    }
    __syncthreads();
    if (t < BN) cur[t] = offs[t] - bb;
    __syncthreads();
    for (int e = t; e < cn; e += 256) {
        int p = staged[bb + e];
        int r = atomicAdd(&cur[p & (BN - 1)], 1);   // LDS atomic
        if (lds_ok) sb[r] = p >> 7;
        else        csr_src[bb + r] = p >> 7;       // improbable fallback
    }
    __threadfence_block();
    __syncthreads();
    if (lds_ok)
        for (int e = t; e < cn; e += 256) csr_src[bb + e] = sb[e];  // coalesced persist
    // ---- aggregation: 8 lanes per node, 32 nodes per pass, 4 passes ----
    int c = t & 7;
#pragma unroll 1
    for (int grp = 0; grp < BN / 32; ++grp) {
        int nl = grp * 32 + (t >> 3);
        int node = j * BN + nl;
        if (node >= NN) continue;
        int ls = offs[nl] - bb, le = offs[nl + 1] - bb;
        float acc[8] = {0, 0, 0, 0, 0, 0, 0, 0};
        acc8(acc, ys4[(size_t)node * 8 + c]);   // self-loop term
        int i = ls;
        int n4 = ls + ((le - ls) & ~3);
        for (; i < n4; i += 4) {
            int s0 = lds_ok ? sb[i]     : csr_src[bb + i];
            int s1 = lds_ok ? sb[i + 1] : csr_src[bb + i + 1];
            int s2 = lds_ok ? sb[i + 2] : csr_src[bb + i + 2];
            int s3 = lds_ok ? sb[i + 3] : csr_src[bb + i + 3];
            uint4 r0 = ys4[(size_t)s0 * 8 + c];
            uint4 r1 = ys4[(size_t)s1 * 8 + c];
            uint4 r2 = ys4[(size_t)s2 * 8 + c];
            uint4 r3 = ys4[(size_t)s3 * 8 + c];
            acc8(acc, r0); acc8(acc, r1); acc8(acc, r2); acc8(acc, r3);
        }
        for (; i < le; ++i) {
            int s = lds_ok ? sb[i] : csr_src[bb + i];
            acc8(acc, ys4[(size_t)s * 8 + c]);
        }
        float ds = rsqrtf((float)(le - ls) + 1.0f);
        const float4 bv0 = *(const float4*)&b[c * 8];
        const float4 bv1 = *(const float4*)&b[c * 8 + 4];
        uint4 o;
        o.x = pack2(fmaxf(fmaf(ds, acc[0], bv0.x), 0.f), fmaxf(fmaf(ds, acc[1], bv0.y), 0.f));
        o.y = pack2(fmaxf(fmaf(ds, acc[2], bv0.z), 0.f), fmaxf(fmaf(ds, acc[3], bv0.w), 0.f));
        o.z = pack2(fmaxf(fmaf(ds, acc[4], bv1.x), 0.f), fmaxf(fmaf(ds, acc[5], bv1.y), 0.f));
        o.w = pack2(fmaxf(fmaf(ds, acc[6], bv1.z), 0.f), fmaxf(fmaf(ds, acc[7], bv1.w), 0.f));
        h4[(size_t)node * 8 + c] = o;
    }
}

// ---------------- matmul 2 (MFMA): ys2 = bf16(dis * (h @ W2)), h bf16 ----------------
__global__ __launch_bounds__(256) void mm2_kernel(const unsigned short* __restrict__ h,
                                                  const float* __restrict__ W,
                                                  const float* __restrict__ dis,
                                                  unsigned short* __restrict__ y) {
    __shared__ unsigned short Wt[32][72];  // W^T bf16: [n][k], pad 8
    int t = threadIdx.x;
    for (int i = t; i < 64 * 32; i += 256) {
        int k = i >> 5, n = i & 31;
        Wt[n][k] = bf16_of(W[i]);
    }
    __syncthreads();
    int wave = t >> 6, lane = t & 63;
    int quad = lane >> 4, n16 = lane & 15;
    short8 bfr[2][2];
#pragma unroll
    for (int s = 0; s < 2; ++s)
#pragma unroll
        for (int tt = 0; tt < 2; ++tt)
            bfr[s][tt] = *(const short8*)&Wt[tt * 16 + n16][s * 32 + quad * 8];
    int tile0 = (blockIdx.x * 4 + wave) * 4;
#pragma unroll 1
    for (int it = 0; it < 4; ++it) {
        int tile = tile0 + it;
        if (tile >= 6250) break;
        int m0 = tile * 16;
        const unsigned short* hp = h + (size_t)(m0 + n16) * 64 + quad * 8;
        floatx4 acc0 = {0,0,0,0}, acc1 = {0,0,0,0};
#pragma unroll
        for (int s = 0; s < 2; ++s) {
            short8 a = *(const short8*)(hp + s * 32);
            acc0 = __builtin_amdgcn_mfma_f32_16x16x32_bf16(a, bfr[s][0], acc0, 0, 0, 0);
            acc1 = __builtin_amdgcn_mfma_f32_16x16x32_bf16(a, bfr[s][1], acc1, 0, 0, 0);
        }
#pragma unroll
        for (int r = 0; r < 4; ++r) {
            int ro = m0 + quad * 4 + r;
            float sc = dis[ro];
            unsigned short* yp = y + (size_t)ro * 32 + n16;
            yp[0]  = bf16_of(acc0[r] * sc);
            yp[16] = bf16_of(acc1[r] * sc);
        }
    }
}

// ---------------- gather-aggregate, dim 32 bf16 -> z f16, unroll 8 ----------------
__global__ __launch_bounds__(256) void agg32_kernel(const uint4* __restrict__ ys4,
                                                    const float* __restrict__ dis,
                                                    const int* __restrict__ offset,
                                                    const int* __restrict__ csr_src,
                                                    const float* __restrict__ b,
                                                    uint4* __restrict__ z4) {
    int tid = blockIdx.x * 256 + threadIdx.x;
    int nd = tid >> 2, c = tid & 3;
    if (nd >= NN) return;
    int start = offset[nd], end = offset[nd + 1];
    float acc[8] = {0, 0, 0, 0, 0, 0, 0, 0};
    acc8(acc, ys4[(size_t)nd * 4 + c]);
    int i = start;
    int n8 = start + ((end - start) & ~7);
    for (; i < n8; i += 8) {
        int s0 = csr_src[i],     s1 = csr_src[i + 1], s2 = csr_src[i + 2], s3 = csr_src[i + 3];
        int s4 = csr_src[i + 4], s5 = csr_src[i + 5], s6 = csr_src[i + 6], s7 = csr_src[i + 7];
        uint4 r0 = ys4[(size_t)s0 * 4 + c];
        uint4 r1 = ys4[(size_t)s1 * 4 + c];
        uint4 r2 = ys4[(size_t)s2 * 4 + c];
        uint4 r3 = ys4[(size_t)s3 * 4 + c];
        uint4 r4 = ys4[(size_t)s4 * 4 + c];
        uint4 r5 = ys4[(size_t)s5 * 4 + c];
        uint4 r6 = ys4[(size_t)s6 * 4 + c];
        uint4 r7 = ys4[(size_t)s7 * 4 + c];
        acc8(acc, r0); acc8(acc, r1); acc8(acc, r2); acc8(acc, r3);
        acc8(acc, r4); acc8(acc, r5); acc8(acc, r6); acc8(acc, r7);
    }
    for (; i < end; ++i) acc8(acc, ys4[(size_t)csr_src[i] * 4 + c]);
    float ds = dis[nd];
    const float4 bv0 = *(const float4*)&b[c * 8];
    const float4 bv1 = *(const float4*)&b[c * 8 + 4];
    uint4 o;  // z stored f16
    o.x = packh2(fmaf(ds, acc[0], bv0.x), fmaf(ds, acc[1], bv0.y));
    o.y = packh2(fmaf(ds, acc[2], bv0.z), fmaf(ds, acc[3], bv0.w));
    o.z = packh2(fmaf(ds, acc[4], bv1.x), fmaf(ds, acc[5], bv1.y));
    o.w = packh2(fmaf(ds, acc[6], bv1.z), fmaf(ds, acc[7], bv1.w));
    z4[(size_t)nd * 4 + c] = o;
}

// ---------------- decode (edge order): sigmoid(dot(z[src],z[dst])), f16 + fdot2 ------
__global__ __launch_bounds__(256) void decode_kernel(const uint4* __restrict__ z4,
                                                     const int* __restrict__ src,
                                                     const int* __restrict__ dst,
                                                     float* __restrict__ out) {
    int tid = blockIdx.x * 256 + threadIdx.x;
    int e = tid >> 2, k = tid & 3;
    if (e >= NE) return;
    int s = src[e], d = dst[e];
    uint4 ra = z4[(size_t)s * 4 + k];
    uint4 rb = z4[(size_t)d * 4 + k];
    float acc = dot2acc(ra.x, rb.x, 0.f);
    acc = dot2acc(ra.y, rb.y, acc);
    acc = dot2acc(ra.z, rb.z, acc);
    acc = dot2acc(ra.w, rb.w, acc);
    acc += __shfl_xor(acc, 1, 4);
    acc += __shfl_xor(acc, 2, 4);
    if (k == 0) out[e] = 1.0f / (1.0f + expf(-acc));
}

// ---------------- launcher ----------------
extern "C" void kernel_launch(void* const* d_in, const int* in_sizes, int n_in,
                              void* d_out, int out_size, void* d_ws, size_t ws_size,
                              hipStream_t stream) {
    const float* emb = (const float*)d_in[0];
    const float* W1  = (const float*)d_in[1];
    const float* b1  = (const float*)d_in[2];
    const float* W2  = (const float*)d_in[3];
    const float* b2  = (const float*)d_in[4];
    const int*   ei  = (const int*)d_in[5];
    const int* src = ei;
    const int* dst = ei + NE;
    float* out = (float*)d_out;

    // workspace layout
    char* w = (char*)d_ws;
    int*   offset      = (int*)w;           w += (size_t)NPAD * 4;
    float* dis         = (float*)w;         w += (size_t)NPAD * 4;
    int*   bucket_base = (int*)w;           w += 4096;
    int*   totals      = (int*)w;           w += 4096;
    int*   blkhist     = (int*)w;           w += (size_t)NB * SBLK * 4 + 1024;  // ~1.63MB
    int*   csr_src     = (int*)w;           w += (size_t)NE * 4;                // 12.8MB
    int*   staged      = (int*)w;           w += (size_t)NE * 4;                // 12.8MB
    unsigned short* ysbuf = (unsigned short*)w; w += (size_t)NN * 64 * 2;       // 12.8MB
    unsigned short* h  = (unsigned short*)w;                                    // 12.8MB
    unsigned short* ys1 = ysbuf;                       // [NN][64] bf16
    unsigned short* ys2 = ysbuf;                       // [NN][32] bf16 (overlay)
    unsigned short* z   = ysbuf + (size_t)NN * 32;     // [NN][32] f16 (2nd half)

    // CSR build
    hist_kernel<<<SBLK, 256, 0, stream>>>(dst, blkhist);
    scanA_kernel<<<NB, 64, 0, stream>>>(blkhist, totals);
    scanB_kernel<<<1, 64, 0, stream>>>(totals, bucket_base);
    scatter_kernel<<<SBLK, 256, 0, stream>>>(src, dst, blkhist, bucket_base, staged);
    degdis_kernel<<<NB, 256, 0, stream>>>(staged, bucket_base, offset, dis);

    // layer 1: mm1 then fused sort+aggregate (also persists csr_src for agg32)
    mm1_kernel<<<391, 256, 0, stream>>>(emb, W1, dis, ys1);
    aggsort64_kernel<<<NB, 256, 0, stream>>>(staged, bucket_base, offset,
                                             (const uint4*)ys1, b1, csr_src, (uint4*)h);

    // layer 2
    mm2_kernel<<<391, 256, 0, stream>>>(h, W2, dis, ys2);
    agg32_kernel<<<(NN * 4 + 255) / 256, 256, 0, stream>>>((const uint4*)ys2, dis, offset,
                                                           csr_src, b2, (uint4*)z);

    // decode (edge order, coalesced out)
    decode_kernel<<<(NE * 4) / 256, 256, 0, stream>>>((const uint4*)z, src, dst, out);
}